// Round 6
// baseline (330.346 us; speedup 1.0000x reference)
//
#include <hip/hip_runtime.h>
#include <math.h>

// NeRF volume rendering: N=65536 rays, S=192 samples.
// v7: compiler-proof software pipeline (triple buffer + sched_barrier).
//
// History: v2 DPP NEUTRAL; v5 dwordx4+NT slightly WORSE (NT stores -9%);
// v6 reg-double-buffer NEUTRAL with VGPR_Count=36 -> the compiler SANK the
// prefetch loads back to right-before-use (a 2-buffer pipeline cannot fit in
// 36 VGPRs). The pipelining theory was never actually tested.
//
// Mechanism being tested: vmcnt is a FIFO over loads AND stores. If next-ray
// loads issue AFTER current-ray stores, every load-wait drains the stores
// through the congested 150MB write path -> per-ray store-latency coupling.
// (Evidence: NT stores, which slow store completion, were the only variant
// that got WORSE.) Fix: triple buffer, phase order loads(r+2) -> compute(r)
// -> stores(r), pinned with sched_barrier(0) so stores always issue after
// any load a future wait targets -> load-waits never wait on stores.
//
// Verification hook: VGPR_Count must be ~80-100. If <=40, barriers failed.

constexpr int kRays = 65536;
constexpr int kS = 192;
constexpr int kRaysPerWave = 8;
constexpr int kWavesPerBlock = 4;
constexpr int kBlocks = kRays / (kRaysPerWave * kWavesPerBlock);  // 2048

typedef float v4f __attribute__((ext_vector_type(4)));

// ---- DPP cross-lane helpers ----
template <int CTRL, int RMASK>
__device__ __forceinline__ float dpp_mul(float v) {
    const int t = __builtin_amdgcn_update_dpp(0x3f800000 /*1.0f*/, __float_as_int(v),
                                              CTRL, RMASK, 0xF, false);
    return v * __int_as_float(t);
}
template <int CTRL, int RMASK>
__device__ __forceinline__ float dpp_add(float v) {
    const int t = __builtin_amdgcn_update_dpp(0 /*0.0f*/, __float_as_int(v),
                                              CTRL, RMASK, 0xF, false);
    return v + __int_as_float(t);
}

// Inclusive 64-lane prefix product (shifts THEN broadcasts; order matters).
__device__ __forceinline__ float scan_mul64(float x) {
    float v = x;
    v = dpp_mul<0x111, 0xF>(v);   // row_shr:1
    v = dpp_mul<0x112, 0xF>(v);   // row_shr:2
    v = dpp_mul<0x114, 0xF>(v);   // row_shr:4
    v = dpp_mul<0x118, 0xF>(v);   // row_shr:8
    v = dpp_mul<0x142, 0xA>(v);   // row_bcast15 (rows 1,3)
    v = dpp_mul<0x143, 0xC>(v);   // row_bcast31 (rows 2,3)
    return v;
}

// 64-lane sum; total lands in lane 63.
__device__ __forceinline__ float red_add64(float x) {
    float v = x;
    v = dpp_add<0x111, 0xF>(v);
    v = dpp_add<0x112, 0xF>(v);
    v = dpp_add<0x114, 0xF>(v);
    v = dpp_add<0x118, 0xF>(v);
    v = dpp_add<0x142, 0xA>(v);
    v = dpp_add<0x143, 0xC>(v);
    return v;
}

// wave_shr:1 -> lane i gets lane i-1; lane 0 gets `fill`.
__device__ __forceinline__ float wave_shr1(float x, float fill) {
    const int t = __builtin_amdgcn_update_dpp(__float_as_int(fill), __float_as_int(x),
                                              0x138, 0xF, 0xF, false);
    return __int_as_float(t);
}
// wave_shl:1 -> lane i gets lane i+1; lane 63 gets `fill`.
__device__ __forceinline__ float wave_shl1(float x, float fill) {
    const int t = __builtin_amdgcn_update_dpp(__float_as_int(fill), __float_as_int(x),
                                              0x130, 0xF, 0xF, false);
    return __int_as_float(t);
}

struct RayRegs {
    v4f zq, sq, c0, c1, c2;   // z[4], sigma[4], rgb[12]
    float dx, dy, dz;         // ray direction
};

__global__ __launch_bounds__(256) void nerf_render_kernel(
    const float* __restrict__ rgb,      // [N, S, 3]
    const float* __restrict__ sigma,    // [N, S]
    const float* __restrict__ z_vals,   // [N, S]
    const float* __restrict__ rays_d,   // [N, 3]
    float* __restrict__ out)
{
    const int lane = threadIdx.x & 63;
    const int wid  = blockIdx.x * kWavesPerBlock + (threadIdx.x >> 6);
    const int ray0 = wid * kRaysPerWave;     // 8 consecutive rays per wave
    const bool act = lane < 48;              // 48 lanes x 4 samples = 192

    float* __restrict__ rgb_map   = out;                                        // [N,3]
    float* __restrict__ depth_map = out + (size_t)kRays * 3;                    // [N]
    float* __restrict__ acc_map   = out + (size_t)kRays * 4;                    // [N]
    float* __restrict__ weights_o = out + (size_t)kRays * 5;                    // [N,S]
    float* __restrict__ disp_map  = out + (size_t)kRays * 5 + (size_t)kRays * kS;      // [N]
    float* __restrict__ trans_o   = out + (size_t)kRays * 6 + (size_t)kRays * kS;      // [N,S]
    float* __restrict__ alpha_o   = out + (size_t)kRays * 6 + (size_t)kRays * kS * 2;  // [N,S]

    auto load_ray = [&](int ray, RayRegs& R) {
        const size_t base = (size_t)ray * kS;
        R.zq = (v4f)(0.f); R.sq = (v4f)(0.f);
        R.c0 = (v4f)(0.f); R.c1 = (v4f)(0.f); R.c2 = (v4f)(0.f);
        if (act) {
            R.zq = *reinterpret_cast<const v4f*>(z_vals + base + 4 * lane);
            R.sq = *reinterpret_cast<const v4f*>(sigma  + base + 4 * lane);
            const float* rp = rgb + base * 3 + 12 * lane;   // 16B-aligned (48B stride)
            R.c0 = *reinterpret_cast<const v4f*>(rp);
            R.c1 = *reinterpret_cast<const v4f*>(rp + 4);
            R.c2 = *reinterpret_cast<const v4f*>(rp + 8);
        }
        R.dx = rays_d[ray * 3 + 0];
        R.dy = rays_d[ray * 3 + 1];
        R.dz = rays_d[ray * 3 + 2];
    };

    // process = compute + store for one ray from one buffer
    auto process_ray = [&](int ray, const RayRegs& A) {
        const float nrm = sqrtf(A.dx * A.dx + A.dy * A.dy + A.dz * A.dz);
        const size_t base = (size_t)ray * kS;

        const float znext = wave_shl1(A.zq[0], 0.f);

        const float zv[4] = {A.zq[0], A.zq[1], A.zq[2], A.zq[3]};
        const float sv[4] = {A.sq[0], A.sq[1], A.sq[2], A.sq[3]};
        const float rv[4] = {A.c0[0], A.c0[3], A.c1[2], A.c2[1]};
        const float gv[4] = {A.c0[1], A.c1[0], A.c1[3], A.c2[2]};
        const float bv[4] = {A.c0[2], A.c1[1], A.c2[0], A.c2[3]};

        float alpha[4], om[4];
        #pragma unroll
        for (int j = 0; j < 4; ++j) {
            const int idx = 4 * lane + j;
            float d;
            if (j < 3)              d = zv[j + 1] - zv[j];
            else if (idx < kS - 1)  d = znext - zv[3];
            else                    d = 1e10f;          // last sample (and idle lanes)
            const float dist = d * nrm;
            const float s = sv[j] > 0.f ? sv[j] : 0.f;  // relu; idle lanes -> alpha=0
            const float e = expf(-s * dist);
            alpha[j] = 1.0f - e;
            om[j]    = 1.0f - alpha[j];                 // match reference rounding
        }

        const float q0 = om[0];
        const float q1 = q0 * om[1];
        const float q2 = q1 * om[2];
        const float q3 = q2 * om[3];
        const float incl = scan_mul64(q3);              // idle lanes contribute 1.0
        const float excl = wave_shr1(incl, 1.0f);

        const float trans[4] = {excl, excl * q0, excl * q1, excl * q2};
        float w[4];
        #pragma unroll
        for (int j = 0; j < 4; ++j) w[j] = alpha[j] * trans[j];

        // per-ray scalar reductions (pure VALU/DPP)
        float sr = 0.f, sg_ = 0.f, sb = 0.f, sd = 0.f, sw = 0.f;
        #pragma unroll
        for (int j = 0; j < 4; ++j) {
            sr  += w[j] * rv[j];
            sg_ += w[j] * gv[j];
            sb  += w[j] * bv[j];
            sd  += w[j] * zv[j];
            sw  += w[j];
        }
        sr  = red_add64(sr);
        sg_ = red_add64(sg_);
        sb  = red_add64(sb);
        sd  = red_add64(sd);
        sw  = red_add64(sw);

        // ---- store phase (issued AFTER all of this iteration's loads) ----
        __builtin_amdgcn_sched_barrier(0);
        if (act) {
            const size_t o = base + 4 * lane;
            v4f tv = {trans[0], trans[1], trans[2], trans[3]};
            v4f av = {alpha[0], alpha[1], alpha[2], alpha[3]};
            v4f wv = {w[0], w[1], w[2], w[3]};
            *reinterpret_cast<v4f*>(trans_o + o)   = tv;
            *reinterpret_cast<v4f*>(alpha_o + o)   = av;
            *reinterpret_cast<v4f*>(weights_o + o) = wv;
        }
        if (lane == 63) {
            rgb_map[ray * 3 + 0] = sr;
            rgb_map[ray * 3 + 1] = sg_;
            rgb_map[ray * 3 + 2] = sb;
            depth_map[ray] = sd;
            acc_map[ray]   = sw;
            const float q = fmaxf(1e-10f, sd / sw);
            disp_map[ray] = 1.0f / q;
        }
    };

    RayRegs buf[3];
    load_ray(ray0 + 0, buf[0]);
    load_ray(ray0 + 1, buf[1]);

    // Fully unrolled so buf indices are compile-time constants (no scratch).
    // Phase order per iteration, pinned by sched_barrier(0):
    //   loads(r+2) -> compute(r) -> stores(r)
    // FIFO consequence: a wait for loads(r) never drains a store.
    #pragma unroll
    for (int r = 0; r < kRaysPerWave; ++r) {
        __builtin_amdgcn_sched_barrier(0);
        if (r + 2 < kRaysPerWave) load_ray(ray0 + r + 2, buf[(r + 2) % 3]);
        __builtin_amdgcn_sched_barrier(0);
        process_ray(ray0 + r, buf[r % 3]);
        __builtin_amdgcn_sched_barrier(0);
    }
}

extern "C" void kernel_launch(void* const* d_in, const int* in_sizes, int n_in,
                              void* d_out, int out_size, void* d_ws, size_t ws_size,
                              hipStream_t stream) {
    const float* rgb    = (const float*)d_in[0];
    const float* sigma  = (const float*)d_in[1];
    const float* z_vals = (const float*)d_in[2];
    const float* rays_d = (const float*)d_in[3];
    float* out = (float*)d_out;

    nerf_render_kernel<<<kBlocks, 256, 0, stream>>>(rgb, sigma, z_vals, rays_d, out);
}